// Round 7
// baseline (533.417 us; speedup 1.0000x reference)
//
#include <hip/hip_runtime.h>
#include <hip/hip_fp16.h>

#define N_NODES 100000
#define N_EDGES 1600000
#define N_GRAPHS 1024
#define DIM_IN 128
#define D1 100
#define D2 20
#define DIM_SF 32
#define DF1 128
#define DF2 32
#define DOUT 8
#define EPS 1e-5f

// ---------------- single-pass binning into fixed-capacity bucket regions ----------------
#define NBK 512                 // buckets: dst / BW
#define BW 196                  // nodes per bucket (512*196 = 100352 >= N_NODES)
#define BKCAP 4096              // region capacity (avg cnt 3136, sigma ~55 -> 17 sigma margin)
#define EPB 4096
#define NBLK1 ((N_EDGES + EPB - 1) / EPB)   // 391

// LDS histogram -> one global atomic per (block,bucket) -> bucket-major LDS staging
// -> ordered write (runs per bucket keep line merging decent). Order within bucket
// irrelevant (bfine2 re-sorts by local dst).
__global__ void __launch_bounds__(256) k_scatter2(const int* __restrict__ src,
                                                  const int* __restrict__ dst,
                                                  int* __restrict__ gcursor,
                                                  unsigned* __restrict__ packed) {
  __shared__ int hist[NBK];
  __shared__ int lbase[NBK];
  __shared__ int gbase[NBK];
  __shared__ int ssum[256];
  __shared__ unsigned sval[EPB];   // 16 KB
  __shared__ int spos[EPB];        // 16 KB
  int t = threadIdx.x, blk = blockIdx.x;
  for (int i = t; i < NBK; i += 256) hist[i] = 0;
  __syncthreads();
  int base = blk * EPB;
  unsigned pk[16]; int bn[16]; int rk[16];
#pragma unroll
  for (int r = 0; r < 16; r++) {
    int e = base + r * 256 + t;
    bn[r] = -1;
    if (e < N_EDGES) {
      int dv = dst[e];
      unsigned b = (unsigned)dv / BW;
      unsigned ld = (unsigned)dv - b * BW;   // < 196, fits 8 bits
      bn[r] = (int)b;
      pk[r] = ((unsigned)src[e] << 8) | ld;
      rk[r] = atomicAdd(&hist[b], 1);
    }
  }
  __syncthreads();
  // exclusive scan of hist (2 bins/thread) for staging order; reserve global ranges
  int h0 = hist[2 * t], h1 = hist[2 * t + 1];
  int s = h0 + h1;
  ssum[t] = s; __syncthreads();
  for (int off = 1; off < 256; off <<= 1) {
    int x = (t >= off) ? ssum[t - off] : 0;
    __syncthreads();
    ssum[t] += x;
    __syncthreads();
  }
  int excl = ssum[t] - s;
  lbase[2 * t] = excl;
  lbase[2 * t + 1] = excl + h0;
  gbase[2 * t]     = (h0 > 0) ? atomicAdd(&gcursor[2 * t], h0) : 0;
  gbase[2 * t + 1] = (h1 > 0) ? atomicAdd(&gcursor[2 * t + 1], h1) : 0;
  __syncthreads();
#pragma unroll
  for (int r = 0; r < 16; r++) {
    if (bn[r] >= 0) {
      int li = lbase[bn[r]] + rk[r];
      sval[li] = pk[r];
      spos[li] = bn[r] * BKCAP + gbase[bn[r]] + rk[r];
    }
  }
  __syncthreads();
  int cnt = N_EDGES - base; if (cnt > EPB) cnt = EPB;
  for (int i = t; i < cnt; i += 256) packed[spos[i]] = sval[i];
}

// per bucket: LDS counting sort by local dst -> region-local CSR + deg + row_off.
__global__ void __launch_bounds__(256) k_bfine2(const unsigned* __restrict__ packed,
                                                const int* __restrict__ gcursor,
                                                int* __restrict__ csr,
                                                int* __restrict__ deg,
                                                int* __restrict__ row_off) {
  __shared__ unsigned sval[BKCAP];  // 16 KB
  __shared__ int scsr[BKCAP];       // 16 KB
  __shared__ int hist[256];
  __shared__ int soff[256];
  __shared__ int cur[256];
  int b = blockIdx.x, t = threadIdx.x;
  int cnt = gcursor[b]; if (cnt > BKCAP) cnt = BKCAP;
  int start = b * BKCAP;
  hist[t] = 0;
  __syncthreads();
  for (int i = t; i < cnt; i += 256) {
    unsigned v = packed[start + i];
    sval[i] = v;
    atomicAdd(&hist[v & 255u], 1);
  }
  __syncthreads();
  int h = hist[t];
  soff[t] = h; __syncthreads();
  for (int off = 1; off < 256; off <<= 1) {
    int x = (t >= off) ? soff[t - off] : 0;
    __syncthreads();
    soff[t] += x;
    __syncthreads();
  }
  int excl = soff[t] - h;
  cur[t] = excl;
  int n = b * BW + t;
  if (t < BW && n < N_NODES) { deg[n] = h; row_off[n] = start + excl; }
  __syncthreads();
  for (int i = t; i < cnt; i += 256) {
    unsigned v = sval[i];
    int pos = atomicAdd(&cur[v & 255u], 1);
    scsr[pos] = (int)(v >> 8);
  }
  __syncthreads();
  for (int i = t; i < cnt; i += 256) csr[start + i] = scsr[i];
}

// ---------------- p1 = fp16(feat @ W1)  (bias applied after aggregation) ----------------
__global__ void __launch_bounds__(256) k_gemm1(const float* __restrict__ feat,
                                               const float* __restrict__ W1,
                                               __half* __restrict__ p1h) {
  __shared__ float w1s[DIM_IN * D1];   // 51.2 KB
  int t = threadIdx.x;
  for (int i = t; i < DIM_IN * D1; i += 256) w1s[i] = W1[i];
  __syncthreads();
  if (t >= 250) return;
  int q = t % 25, ng = t / 25;
  int n0 = blockIdx.x * 80 + ng * 8;   // grid 1250 -> exactly 100000 nodes
  int c0 = q * 4;
  float acc[8][4] = {{0.f}};
  const float* f0 = feat + (size_t)n0 * DIM_IN;
  for (int k = 0; k < DIM_IN; k += 4) {
    float4 w0 = *(const float4*)&w1s[(k + 0) * D1 + c0];
    float4 w1 = *(const float4*)&w1s[(k + 1) * D1 + c0];
    float4 w2 = *(const float4*)&w1s[(k + 2) * D1 + c0];
    float4 w3 = *(const float4*)&w1s[(k + 3) * D1 + c0];
#pragma unroll
    for (int j = 0; j < 8; j++) {
      float4 f = *(const float4*)(f0 + j * DIM_IN + k);
      acc[j][0] += f.x * w0.x + f.y * w1.x + f.z * w2.x + f.w * w3.x;
      acc[j][1] += f.x * w0.y + f.y * w1.y + f.z * w2.y + f.w * w3.y;
      acc[j][2] += f.x * w0.z + f.y * w1.z + f.z * w2.z + f.w * w3.z;
      acc[j][3] += f.x * w0.w + f.y * w1.w + f.z * w2.w + f.w * w3.w;
    }
  }
#pragma unroll
  for (int j = 0; j < 8; j++) {
    __half2* d2 = (__half2*)(p1h + (size_t)(n0 + j) * D1 + c0);
    d2[0] = __floats2half2_rn(acc[j][0], acc[j][1]);
    d2[1] = __floats2half2_rn(acc[j][2], acc[j][3]);
  }
}

// ---------- agg1 (mean of fp16 p1 over in-edges) + b1 + relu + GEMM2 -> fp16 p2 ----------
// R3-proven mapping (lane<50 owns one half2 column pair). fp16 (__hadd2) accumulation:
// 1 VALU/edge/lane instead of 2 cvt + 2 f32 add.
__global__ void __launch_bounds__(256) k_agg1(const __half* __restrict__ p1h,
                                              const int* __restrict__ deg,
                                              const int* __restrict__ row_off,
                                              const int* __restrict__ csr,
                                              const float* __restrict__ b1,
                                              const float* __restrict__ W2,
                                              __half* __restrict__ p2h) {
  __shared__ float w2s[D1 * D2];
  __shared__ float b1s[D1];
  __shared__ float hbuf[4][104];
  int t = threadIdx.x;
  for (int i = t; i < D1 * D2; i += 256) w2s[i] = W2[i];
  if (t < D1) b1s[t] = b1[t];
  __syncthreads();
  int w = t >> 6, lane = t & 63;
  int n = blockIdx.x * 4 + w;          // grid = 25000 -> exactly N_NODES
  int d = deg[n], ro = row_off[n];
  bool act = lane < 50;
  float ax = 0.f, ay = 0.f;
  if (d > 0) {
    __half2 ah0 = __float2half2_rn(0.f);
    __half2 ah1 = __float2half2_rn(0.f);
    for (int base = 0; base < d; base += 64) {
      int m = d - base; if (m > 64) m = 64;
      int sv = (lane < m) ? csr[ro + base + lane] : 0;   // cooperative index prefetch
      int j = 0;
      for (; j + 7 < m; j += 8) {
        int s0 = __shfl(sv, j),     s1 = __shfl(sv, j + 1);
        int s2 = __shfl(sv, j + 2), s3 = __shfl(sv, j + 3);
        int s4 = __shfl(sv, j + 4), s5 = __shfl(sv, j + 5);
        int s6 = __shfl(sv, j + 6), s7 = __shfl(sv, j + 7);
        if (act) {
          __half2 v0 = ((const __half2*)(p1h + (size_t)s0 * D1))[lane];
          __half2 v1 = ((const __half2*)(p1h + (size_t)s1 * D1))[lane];
          __half2 v2 = ((const __half2*)(p1h + (size_t)s2 * D1))[lane];
          __half2 v3 = ((const __half2*)(p1h + (size_t)s3 * D1))[lane];
          __half2 v4 = ((const __half2*)(p1h + (size_t)s4 * D1))[lane];
          __half2 v5 = ((const __half2*)(p1h + (size_t)s5 * D1))[lane];
          __half2 v6 = ((const __half2*)(p1h + (size_t)s6 * D1))[lane];
          __half2 v7 = ((const __half2*)(p1h + (size_t)s7 * D1))[lane];
          ah0 = __hadd2(ah0, __hadd2(__hadd2(v0, v1), __hadd2(v2, v3)));
          ah1 = __hadd2(ah1, __hadd2(__hadd2(v4, v5), __hadd2(v6, v7)));
        }
      }
      for (; j + 1 < m; j += 2) {
        int s0 = __shfl(sv, j), s1 = __shfl(sv, j + 1);
        if (act) {
          __half2 v0 = ((const __half2*)(p1h + (size_t)s0 * D1))[lane];
          __half2 v1 = ((const __half2*)(p1h + (size_t)s1 * D1))[lane];
          ah0 = __hadd2(ah0, __hadd2(v0, v1));
        }
      }
      if (j < m) {
        int s0 = __shfl(sv, j);
        if (act) {
          __half2 v0 = ((const __half2*)(p1h + (size_t)s0 * D1))[lane];
          ah1 = __hadd2(ah1, v0);
        }
      }
    }
    float2 a0 = __half22float2(ah0);
    float2 a1 = __half22float2(ah1);
    float inv = 1.0f / (float)d;
    ax = (a0.x + a1.x) * inv;
    ay = (a0.y + a1.y) * inv;
  } else if (act) {
    float2 v = __half22float2(((const __half2*)(p1h + (size_t)n * D1))[lane]);
    ax = v.x; ay = v.y;
  }
  if (act) {
    int c = lane * 2;
    hbuf[w][c]     = fmaxf(ax + b1s[c], 0.f);
    hbuf[w][c + 1] = fmaxf(ay + b1s[c + 1], 0.f);
  }
  __syncthreads();
  if (lane < D2) {
    float acc = 0.f;
#pragma unroll 4
    for (int c = 0; c < D1; c++) acc += hbuf[w][c] * w2s[c * D2 + lane];
    p2h[(size_t)n * 32 + lane] = __float2half_rn(acc);   // padded stride 32; b2 in agg2
  }
}

// ---------- agg2: wave-per-node, 6 subgroups x 10 lanes, half2 loads on 64B rows ----------
// + b2 + relu + graph-pool atomics. fp16 accumulation, LDS float2 reduction over subs.
__global__ void __launch_bounds__(256) k_agg2(const __half* __restrict__ p2h,
                                              const int* __restrict__ deg,
                                              const int* __restrict__ row_off,
                                              const int* __restrict__ csr,
                                              const float* __restrict__ b2,
                                              const int* __restrict__ n2g,
                                              float* __restrict__ hg_sum,
                                              int* __restrict__ gcnt) {
  __shared__ float2 red[4][6][10];
  int t = threadIdx.x;
  int w = t >> 6, lane = t & 63;
  int n = blockIdx.x * 4 + w;          // grid = 25000 -> exactly N_NODES
  int d = deg[n], ro = row_off[n];
  int sub = lane / 10;                 // 0..5 active, 6 for lanes 60-63
  int cl = lane - sub * 10;            // 0..9
  bool act = sub < 6;
  __half2 ah = __float2half2_rn(0.f);
  if (d > 0) {
    for (int base = 0; base < d; base += 64) {
      int m = d - base; if (m > 64) m = 64;
      int sv = (lane < m) ? csr[ro + base + lane] : 0;
      int j = 0;
      for (; j + 5 < m; j += 6) {
        int sa = __shfl(sv, (j + sub) & 63);
        if (act) {
          __half2 v = *(const __half2*)(p2h + (size_t)sa * 32 + cl * 2);
          ah = __hadd2(ah, v);
        }
      }
      if (j < m) {                      // leftover 1..5 edges
        int sa = __shfl(sv, (j + sub) & 63);
        if (act && (j + sub) < m) {
          __half2 v = *(const __half2*)(p2h + (size_t)sa * 32 + cl * 2);
          ah = __hadd2(ah, v);
        }
      }
    }
  } else if (sub == 0) {                // fallback: own row (cols 0..19)
    ah = *(const __half2*)(p2h + (size_t)n * 32 + cl * 2);
  }
  if (act) red[w][sub][cl] = __half22float2(ah);
  __syncthreads();
  if (lane < 10) {
    float sx = 0.f, sy = 0.f;
#pragma unroll
    for (int s6 = 0; s6 < 6; s6++) {
      float2 v = red[w][s6][lane];
      sx += v.x; sy += v.y;
    }
    float inv = (d > 0) ? 1.0f / (float)d : 1.0f;
    int c = lane * 2;
    float v0 = fmaxf(sx * inv + b2[c], 0.f);
    float v1 = fmaxf(sy * inv + b2[c + 1], 0.f);
    int g = n2g[n];
    atomicAdd(&hg_sum[g * D2 + c], v0);
    atomicAdd(&hg_sum[g * D2 + c + 1], v1);
    if (lane == 0) atomicAdd(&gcnt[g], 1);
  }
}

// ---------- head ----------
__global__ void __launch_bounds__(128) k_mlp1(const float* __restrict__ hg_sum,
                                              const int* __restrict__ gcnt,
                                              const float* __restrict__ sf,
                                              const float* __restrict__ Wf1,
                                              const float* __restrict__ bf1,
                                              float* __restrict__ y1) {
  __shared__ float prod[D2 * DIM_SF];
  __shared__ float hgl[D2], sfl[DIM_SF];
  int g = blockIdx.x, t = threadIdx.x;
  float cnt = (float)gcnt[g]; if (cnt < 1.f) cnt = 1.f;
  if (t < D2) hgl[t] = hg_sum[g * D2 + t] / cnt;
  if (t < DIM_SF) sfl[t] = sf[g * DIM_SF + t];
  __syncthreads();
  for (int i = t; i < D2 * DIM_SF; i += 128) prod[i] = hgl[i >> 5] * sfl[i & 31];
  __syncthreads();
  float acc = bf1[t];
#pragma unroll 4
  for (int k = 0; k < D2 * DIM_SF; k++) acc += prod[k] * Wf1[k * DF1 + t];
  y1[g * DF1 + t] = acc;
}

__global__ void k_bnstats(const float* __restrict__ x, int ld,
                          float* __restrict__ mu, float* __restrict__ rstd) {
  __shared__ float ssum[256], ssq[256];
  int c = blockIdx.x, t = threadIdx.x;
  float s = 0.f, q = 0.f;
  for (int r = t; r < N_GRAPHS; r += 256) { float v = x[r * ld + c]; s += v; q += v * v; }
  ssum[t] = s; ssq[t] = q; __syncthreads();
  for (int off = 128; off > 0; off >>= 1) {
    if (t < off) { ssum[t] += ssum[t + off]; ssq[t] += ssq[t + off]; }
    __syncthreads();
  }
  if (t == 0) {
    float m = ssum[0] / (float)N_GRAPHS;
    float var = ssq[0] / (float)N_GRAPHS - m * m;
    mu[c] = m;
    rstd[c] = rsqrtf(var + EPS);
  }
}

__global__ void k_mlp2(const float* __restrict__ y1, const float* __restrict__ mu1,
                       const float* __restrict__ rstd1, const float* __restrict__ g1,
                       const float* __restrict__ be1, const float* __restrict__ Wf2,
                       const float* __restrict__ bf2, float* __restrict__ y2) {
  int idx = blockIdx.x * 256 + threadIdx.x;
  int g = idx >> 5, o = idx & 31;
  float acc = bf2[o];
  for (int k = 0; k < DF1; k++) {
    float x = (y1[g * DF1 + k] - mu1[k]) * rstd1[k] * g1[k] + be1[k];
    x = fmaxf(x, 0.f);
    acc += x * Wf2[k * DF2 + o];
  }
  y2[g * DF2 + o] = acc;
}

__global__ void k_mlp3(const float* __restrict__ y2, const float* __restrict__ mu2,
                       const float* __restrict__ rstd2, const float* __restrict__ g2,
                       const float* __restrict__ be2, const float* __restrict__ Wf3,
                       const float* __restrict__ bf3, float* __restrict__ out) {
  int idx = blockIdx.x * 256 + threadIdx.x;
  int g = idx >> 3, o = idx & 7;
  float acc = bf3[o];
  for (int k = 0; k < DF2; k++) {
    float x = (y2[g * DF2 + k] - mu2[k]) * rstd2[k] * g2[k] + be2[k];
    x = fmaxf(x, 0.f);
    acc += x * Wf3[k * DOUT + o];
  }
  out[g * DOUT + o] = acc;
}

extern "C" void kernel_launch(void* const* d_in, const int* in_sizes, int n_in,
                              void* d_out, int out_size, void* d_ws, size_t ws_size,
                              hipStream_t stream) {
  const float* feat = (const float*)d_in[0];
  const float* sf   = (const float*)d_in[1];
  const int*   src  = (const int*)d_in[2];
  const int*   dst  = (const int*)d_in[3];
  const int*   n2g  = (const int*)d_in[4];
  const float* W1   = (const float*)d_in[5];
  const float* b1   = (const float*)d_in[6];
  const float* W2   = (const float*)d_in[7];
  const float* b2   = (const float*)d_in[8];
  const float* Wf1  = (const float*)d_in[9];
  const float* bf1  = (const float*)d_in[10];
  const float* g1   = (const float*)d_in[11];
  const float* be1  = (const float*)d_in[12];
  const float* Wf2  = (const float*)d_in[13];
  const float* bf2  = (const float*)d_in[14];
  const float* g2   = (const float*)d_in[15];
  const float* be2  = (const float*)d_in[16];
  const float* Wf3  = (const float*)d_in[17];
  const float* bf3  = (const float*)d_in[18];
  float* out = (float*)d_out;

  char* ws = (char*)d_ws;
  size_t off = 0;
  auto alloc = [&](size_t bytes) -> void* {
    void* p = ws + off;
    off = (off + bytes + 255) & ~(size_t)255;
    return p;
  };
  // zero-init region first (gcursor, gcnt, hg_sum)
  int*      gcursor = (int*)alloc(NBK * 4);
  int*      gcnt    = (int*)alloc(N_GRAPHS * 4);
  float*    hg_sum  = (float*)alloc(N_GRAPHS * D2 * 4);
  size_t zero_bytes = off;
  int*      deg     = (int*)alloc(N_NODES * 4);
  int*      row_off = (int*)alloc(N_NODES * 4);
  unsigned* packed  = (unsigned*)alloc((size_t)NBK * BKCAP * 4);
  int*      csr     = (int*)alloc((size_t)NBK * BKCAP * 4);
  __half*   p1h     = (__half*)alloc((size_t)N_NODES * D1 * 2);
  __half*   p2h     = (__half*)alloc((size_t)N_NODES * 32 * 2);   // padded rows (64B)
  float*    y1      = (float*)alloc((size_t)N_GRAPHS * DF1 * 4);
  float*    y2      = (float*)alloc((size_t)N_GRAPHS * DF2 * 4);
  float*    mu1     = (float*)alloc(DF1 * 4);
  float*    rstd1   = (float*)alloc(DF1 * 4);
  float*    mu2     = (float*)alloc(DF2 * 4);
  float*    rstd2   = (float*)alloc(DF2 * 4);

  hipMemsetAsync(d_ws, 0, zero_bytes, stream);

  k_scatter2<<<NBLK1, 256, 0, stream>>>(src, dst, gcursor, packed);
  k_bfine2<<<NBK, 256, 0, stream>>>(packed, gcursor, csr, deg, row_off);
  k_gemm1<<<N_NODES / 80, 256, 0, stream>>>(feat, W1, p1h);
  k_agg1<<<N_NODES / 4, 256, 0, stream>>>(p1h, deg, row_off, csr, b1, W2, p2h);
  k_agg2<<<N_NODES / 4, 256, 0, stream>>>(p2h, deg, row_off, csr, b2, n2g, hg_sum, gcnt);
  k_mlp1<<<N_GRAPHS, 128, 0, stream>>>(hg_sum, gcnt, sf, Wf1, bf1, y1);
  k_bnstats<<<DF1, 256, 0, stream>>>(y1, DF1, mu1, rstd1);
  k_mlp2<<<(N_GRAPHS * DF2) / 256, 256, 0, stream>>>(y1, mu1, rstd1, g1, be1, Wf2, bf2, y2);
  k_bnstats<<<DF2, 256, 0, stream>>>(y2, DF2, mu2, rstd2);
  k_mlp3<<<(N_GRAPHS * DOUT) / 256, 256, 0, stream>>>(y2, mu2, rstd2, g2, be2, Wf3, bf3, out);
}

// Round 8
// 492.411 us; speedup vs baseline: 1.0833x; 1.0833x over previous
//
#include <hip/hip_runtime.h>
#include <hip/hip_fp16.h>

#define N_NODES 100000
#define N_EDGES 1600000
#define N_GRAPHS 1024
#define DIM_IN 128
#define D1 100
#define D2 20
#define DIM_SF 32
#define DF1 128
#define DF2 32
#define DOUT 8
#define EPS 1e-5f

// ---------------- single-pass binning into fixed-capacity bucket regions ----------------
#define NBK 512                 // buckets: dst / BW
#define BW 196                  // nodes per bucket (512*196 = 100352 >= N_NODES)
#define BKCAP 4096              // region capacity (avg cnt 3136, sigma ~55)
#define EPB 4096
#define NBLK1 ((N_EDGES + EPB - 1) / EPB)   // 391

__global__ void __launch_bounds__(256) k_scatter2(const int* __restrict__ src,
                                                  const int* __restrict__ dst,
                                                  int* __restrict__ gcursor,
                                                  unsigned* __restrict__ packed) {
  __shared__ int hist[NBK];
  __shared__ int lbase[NBK];
  __shared__ int gbase[NBK];
  __shared__ int ssum[256];
  __shared__ unsigned sval[EPB];   // 16 KB
  __shared__ int spos[EPB];        // 16 KB
  int t = threadIdx.x, blk = blockIdx.x;
  for (int i = t; i < NBK; i += 256) hist[i] = 0;
  __syncthreads();
  int base = blk * EPB;
  unsigned pk[16]; int bn[16]; int rk[16];
#pragma unroll
  for (int r = 0; r < 16; r++) {
    int e = base + r * 256 + t;
    bn[r] = -1;
    if (e < N_EDGES) {
      int dv = dst[e];
      unsigned b = (unsigned)dv / BW;
      unsigned ld = (unsigned)dv - b * BW;   // < 196, fits 8 bits
      bn[r] = (int)b;
      pk[r] = ((unsigned)src[e] << 8) | ld;
      rk[r] = atomicAdd(&hist[b], 1);
    }
  }
  __syncthreads();
  int h0 = hist[2 * t], h1 = hist[2 * t + 1];
  int s = h0 + h1;
  ssum[t] = s; __syncthreads();
  for (int off = 1; off < 256; off <<= 1) {
    int x = (t >= off) ? ssum[t - off] : 0;
    __syncthreads();
    ssum[t] += x;
    __syncthreads();
  }
  int excl = ssum[t] - s;
  lbase[2 * t] = excl;
  lbase[2 * t + 1] = excl + h0;
  gbase[2 * t]     = (h0 > 0) ? atomicAdd(&gcursor[2 * t], h0) : 0;
  gbase[2 * t + 1] = (h1 > 0) ? atomicAdd(&gcursor[2 * t + 1], h1) : 0;
  __syncthreads();
#pragma unroll
  for (int r = 0; r < 16; r++) {
    if (bn[r] >= 0) {
      int li = lbase[bn[r]] + rk[r];
      sval[li] = pk[r];
      spos[li] = bn[r] * BKCAP + gbase[bn[r]] + rk[r];
    }
  }
  __syncthreads();
  int cnt = N_EDGES - base; if (cnt > EPB) cnt = EPB;
  for (int i = t; i < cnt; i += 256) packed[spos[i]] = sval[i];
}

// per bucket: LDS counting sort by local dst -> region-local CSR + deg + row_off.
__global__ void __launch_bounds__(256) k_bfine2(const unsigned* __restrict__ packed,
                                                const int* __restrict__ gcursor,
                                                int* __restrict__ csr,
                                                int* __restrict__ deg,
                                                int* __restrict__ row_off) {
  __shared__ unsigned sval[BKCAP];  // 16 KB
  __shared__ int scsr[BKCAP];       // 16 KB
  __shared__ int hist[256];
  __shared__ int soff[256];
  __shared__ int cur[256];
  int b = blockIdx.x, t = threadIdx.x;
  int cnt = gcursor[b]; if (cnt > BKCAP) cnt = BKCAP;
  int start = b * BKCAP;
  hist[t] = 0;
  __syncthreads();
  for (int i = t; i < cnt; i += 256) {
    unsigned v = packed[start + i];
    sval[i] = v;
    atomicAdd(&hist[v & 255u], 1);
  }
  __syncthreads();
  int h = hist[t];
  soff[t] = h; __syncthreads();
  for (int off = 1; off < 256; off <<= 1) {
    int x = (t >= off) ? soff[t - off] : 0;
    __syncthreads();
    soff[t] += x;
    __syncthreads();
  }
  int excl = soff[t] - h;
  cur[t] = excl;
  int n = b * BW + t;
  if (t < BW && n < N_NODES) { deg[n] = h; row_off[n] = start + excl; }
  __syncthreads();
  for (int i = t; i < cnt; i += 256) {
    unsigned v = sval[i];
    int pos = atomicAdd(&cur[v & 255u], 1);
    scsr[pos] = (int)(v >> 8);
  }
  __syncthreads();
  for (int i = t; i < cnt; i += 256) csr[start + i] = scsr[i];
}

// ---------------- p1 = fp16(feat @ W1)  (bias applied after aggregation) ----------------
__global__ void __launch_bounds__(256) k_gemm1(const float* __restrict__ feat,
                                               const float* __restrict__ W1,
                                               __half* __restrict__ p1h) {
  __shared__ float w1s[DIM_IN * D1];   // 51.2 KB
  int t = threadIdx.x;
  for (int i = t; i < DIM_IN * D1; i += 256) w1s[i] = W1[i];
  __syncthreads();
  if (t >= 250) return;
  int q = t % 25, ng = t / 25;
  int n0 = blockIdx.x * 80 + ng * 8;   // grid 1250 -> exactly 100000 nodes
  int c0 = q * 4;
  float acc[8][4] = {{0.f}};
  const float* f0 = feat + (size_t)n0 * DIM_IN;
  for (int k = 0; k < DIM_IN; k += 4) {
    float4 w0 = *(const float4*)&w1s[(k + 0) * D1 + c0];
    float4 w1 = *(const float4*)&w1s[(k + 1) * D1 + c0];
    float4 w2 = *(const float4*)&w1s[(k + 2) * D1 + c0];
    float4 w3 = *(const float4*)&w1s[(k + 3) * D1 + c0];
#pragma unroll
    for (int j = 0; j < 8; j++) {
      float4 f = *(const float4*)(f0 + j * DIM_IN + k);
      acc[j][0] += f.x * w0.x + f.y * w1.x + f.z * w2.x + f.w * w3.x;
      acc[j][1] += f.x * w0.y + f.y * w1.y + f.z * w2.y + f.w * w3.y;
      acc[j][2] += f.x * w0.z + f.y * w1.z + f.z * w2.z + f.w * w3.z;
      acc[j][3] += f.x * w0.w + f.y * w1.w + f.z * w2.w + f.w * w3.w;
    }
  }
#pragma unroll
  for (int j = 0; j < 8; j++) {
    __half2* d2 = (__half2*)(p1h + (size_t)(n0 + j) * D1 + c0);
    d2[0] = __floats2half2_rn(acc[j][0], acc[j][1]);
    d2[1] = __floats2half2_rn(acc[j][2], acc[j][3]);
  }
}

// ---------- agg1 (mean of fp16 p1 over in-edges) + b1 + relu + GEMM2 -> fp16 p2 ----------
// R3-proven mapping (lane<50 owns one half2 column pair), fp16 (__hadd2) accumulation.
__global__ void __launch_bounds__(256) k_agg1(const __half* __restrict__ p1h,
                                              const int* __restrict__ deg,
                                              const int* __restrict__ row_off,
                                              const int* __restrict__ csr,
                                              const float* __restrict__ b1,
                                              const float* __restrict__ W2,
                                              __half* __restrict__ p2h) {
  __shared__ float w2s[D1 * D2];
  __shared__ float b1s[D1];
  __shared__ float hbuf[4][104];
  int t = threadIdx.x;
  for (int i = t; i < D1 * D2; i += 256) w2s[i] = W2[i];
  if (t < D1) b1s[t] = b1[t];
  __syncthreads();
  int w = t >> 6, lane = t & 63;
  int n = blockIdx.x * 4 + w;          // grid = 25000 -> exactly N_NODES
  int d = deg[n], ro = row_off[n];
  bool act = lane < 50;
  float ax = 0.f, ay = 0.f;
  if (d > 0) {
    __half2 ah0 = __float2half2_rn(0.f);
    __half2 ah1 = __float2half2_rn(0.f);
    for (int base = 0; base < d; base += 64) {
      int m = d - base; if (m > 64) m = 64;
      int sv = (lane < m) ? csr[ro + base + lane] : 0;   // cooperative index prefetch
      int j = 0;
      for (; j + 7 < m; j += 8) {
        int s0 = __shfl(sv, j),     s1 = __shfl(sv, j + 1);
        int s2 = __shfl(sv, j + 2), s3 = __shfl(sv, j + 3);
        int s4 = __shfl(sv, j + 4), s5 = __shfl(sv, j + 5);
        int s6 = __shfl(sv, j + 6), s7 = __shfl(sv, j + 7);
        if (act) {
          __half2 v0 = ((const __half2*)(p1h + (size_t)s0 * D1))[lane];
          __half2 v1 = ((const __half2*)(p1h + (size_t)s1 * D1))[lane];
          __half2 v2 = ((const __half2*)(p1h + (size_t)s2 * D1))[lane];
          __half2 v3 = ((const __half2*)(p1h + (size_t)s3 * D1))[lane];
          __half2 v4 = ((const __half2*)(p1h + (size_t)s4 * D1))[lane];
          __half2 v5 = ((const __half2*)(p1h + (size_t)s5 * D1))[lane];
          __half2 v6 = ((const __half2*)(p1h + (size_t)s6 * D1))[lane];
          __half2 v7 = ((const __half2*)(p1h + (size_t)s7 * D1))[lane];
          ah0 = __hadd2(ah0, __hadd2(__hadd2(v0, v1), __hadd2(v2, v3)));
          ah1 = __hadd2(ah1, __hadd2(__hadd2(v4, v5), __hadd2(v6, v7)));
        }
      }
      for (; j + 1 < m; j += 2) {
        int s0 = __shfl(sv, j), s1 = __shfl(sv, j + 1);
        if (act) {
          __half2 v0 = ((const __half2*)(p1h + (size_t)s0 * D1))[lane];
          __half2 v1 = ((const __half2*)(p1h + (size_t)s1 * D1))[lane];
          ah0 = __hadd2(ah0, __hadd2(v0, v1));
        }
      }
      if (j < m) {
        int s0 = __shfl(sv, j);
        if (act) {
          __half2 v0 = ((const __half2*)(p1h + (size_t)s0 * D1))[lane];
          ah1 = __hadd2(ah1, v0);
        }
      }
    }
    float2 a0 = __half22float2(ah0);
    float2 a1 = __half22float2(ah1);
    float inv = 1.0f / (float)d;
    ax = (a0.x + a1.x) * inv;
    ay = (a0.y + a1.y) * inv;
  } else if (act) {
    float2 v = __half22float2(((const __half2*)(p1h + (size_t)n * D1))[lane]);
    ax = v.x; ay = v.y;
  }
  if (act) {
    int c = lane * 2;
    hbuf[w][c]     = fmaxf(ax + b1s[c], 0.f);
    hbuf[w][c + 1] = fmaxf(ay + b1s[c + 1], 0.f);
  }
  __syncthreads();
  if (lane < D2) {
    float acc = 0.f;
#pragma unroll 4
    for (int c = 0; c < D1; c++) acc += hbuf[w][c] * w2s[c * D2 + lane];
    p2h[(size_t)n * 32 + lane] = __float2half_rn(acc);   // padded stride 32; b2 in agg2
  }
}

// ---------- agg2: R3-proven thread-parallel pull (10 threads/node, half2 col pair) ----------
// padded 64B rows -> each edge touches exactly one line; 4-wide independent unroll.
__global__ void __launch_bounds__(256) k_agg2(const __half* __restrict__ p2h,
                                              const int* __restrict__ deg,
                                              const int* __restrict__ row_off,
                                              const int* __restrict__ csr,
                                              const float* __restrict__ b2,
                                              const int* __restrict__ n2g,
                                              float* __restrict__ hg_sum,
                                              int* __restrict__ gcnt) {
  int idx = blockIdx.x * 256 + threadIdx.x;
  int n = idx / 10, cp = idx - (idx / 10) * 10;
  if (n >= N_NODES) return;
  int d = deg[n], ro = row_off[n];
  float sx, sy;
  if (d > 0) {
    __half2 a0 = __float2half2_rn(0.f), a1 = a0, a2 = a0, a3 = a0;
    int e = 0;
    for (; e + 3 < d; e += 4) {
      int s0 = csr[ro + e],     s1 = csr[ro + e + 1];
      int s2 = csr[ro + e + 2], s3 = csr[ro + e + 3];
      a0 = __hadd2(a0, *(const __half2*)(p2h + (size_t)s0 * 32 + cp * 2));
      a1 = __hadd2(a1, *(const __half2*)(p2h + (size_t)s1 * 32 + cp * 2));
      a2 = __hadd2(a2, *(const __half2*)(p2h + (size_t)s2 * 32 + cp * 2));
      a3 = __hadd2(a3, *(const __half2*)(p2h + (size_t)s3 * 32 + cp * 2));
    }
    for (; e < d; e++)
      a0 = __hadd2(a0, *(const __half2*)(p2h + (size_t)csr[ro + e] * 32 + cp * 2));
    float2 f = __half22float2(__hadd2(__hadd2(a0, a1), __hadd2(a2, a3)));
    float inv = 1.0f / (float)d;
    sx = f.x * inv; sy = f.y * inv;
  } else {
    float2 f = __half22float2(*(const __half2*)(p2h + (size_t)n * 32 + cp * 2));
    sx = f.x; sy = f.y;
  }
  int c = cp * 2;
  float v0 = fmaxf(sx + b2[c], 0.f);
  float v1 = fmaxf(sy + b2[c + 1], 0.f);
  int g = n2g[n];
  atomicAdd(&hg_sum[g * D2 + c], v0);
  atomicAdd(&hg_sum[g * D2 + c + 1], v1);
  if (cp == 0) atomicAdd(&gcnt[g], 1);
}

// ---------- head ----------
__global__ void __launch_bounds__(128) k_mlp1(const float* __restrict__ hg_sum,
                                              const int* __restrict__ gcnt,
                                              const float* __restrict__ sf,
                                              const float* __restrict__ Wf1,
                                              const float* __restrict__ bf1,
                                              float* __restrict__ y1) {
  __shared__ float prod[D2 * DIM_SF];
  __shared__ float hgl[D2], sfl[DIM_SF];
  int g = blockIdx.x, t = threadIdx.x;
  float cnt = (float)gcnt[g]; if (cnt < 1.f) cnt = 1.f;
  if (t < D2) hgl[t] = hg_sum[g * D2 + t] / cnt;
  if (t < DIM_SF) sfl[t] = sf[g * DIM_SF + t];
  __syncthreads();
  for (int i = t; i < D2 * DIM_SF; i += 128) prod[i] = hgl[i >> 5] * sfl[i & 31];
  __syncthreads();
  float acc = bf1[t];
#pragma unroll 4
  for (int k = 0; k < D2 * DIM_SF; k++) acc += prod[k] * Wf1[k * DF1 + t];
  y1[g * DF1 + t] = acc;
}

__global__ void k_bnstats(const float* __restrict__ x, int ld,
                          float* __restrict__ mu, float* __restrict__ rstd) {
  __shared__ float ssum[256], ssq[256];
  int c = blockIdx.x, t = threadIdx.x;
  float s = 0.f, q = 0.f;
  for (int r = t; r < N_GRAPHS; r += 256) { float v = x[r * ld + c]; s += v; q += v * v; }
  ssum[t] = s; ssq[t] = q; __syncthreads();
  for (int off = 128; off > 0; off >>= 1) {
    if (t < off) { ssum[t] += ssum[t + off]; ssq[t] += ssq[t + off]; }
    __syncthreads();
  }
  if (t == 0) {
    float m = ssum[0] / (float)N_GRAPHS;
    float var = ssq[0] / (float)N_GRAPHS - m * m;
    mu[c] = m;
    rstd[c] = rsqrtf(var + EPS);
  }
}

__global__ void k_mlp2(const float* __restrict__ y1, const float* __restrict__ mu1,
                       const float* __restrict__ rstd1, const float* __restrict__ g1,
                       const float* __restrict__ be1, const float* __restrict__ Wf2,
                       const float* __restrict__ bf2, float* __restrict__ y2) {
  int idx = blockIdx.x * 256 + threadIdx.x;
  int g = idx >> 5, o = idx & 31;
  float acc = bf2[o];
  for (int k = 0; k < DF1; k++) {
    float x = (y1[g * DF1 + k] - mu1[k]) * rstd1[k] * g1[k] + be1[k];
    x = fmaxf(x, 0.f);
    acc += x * Wf2[k * DF2 + o];
  }
  y2[g * DF2 + o] = acc;
}

__global__ void k_mlp3(const float* __restrict__ y2, const float* __restrict__ mu2,
                       const float* __restrict__ rstd2, const float* __restrict__ g2,
                       const float* __restrict__ be2, const float* __restrict__ Wf3,
                       const float* __restrict__ bf3, float* __restrict__ out) {
  int idx = blockIdx.x * 256 + threadIdx.x;
  int g = idx >> 3, o = idx & 7;
  float acc = bf3[o];
  for (int k = 0; k < DF2; k++) {
    float x = (y2[g * DF2 + k] - mu2[k]) * rstd2[k] * g2[k] + be2[k];
    x = fmaxf(x, 0.f);
    acc += x * Wf3[k * DOUT + o];
  }
  out[g * DOUT + o] = acc;
}

extern "C" void kernel_launch(void* const* d_in, const int* in_sizes, int n_in,
                              void* d_out, int out_size, void* d_ws, size_t ws_size,
                              hipStream_t stream) {
  const float* feat = (const float*)d_in[0];
  const float* sf   = (const float*)d_in[1];
  const int*   src  = (const int*)d_in[2];
  const int*   dst  = (const int*)d_in[3];
  const int*   n2g  = (const int*)d_in[4];
  const float* W1   = (const float*)d_in[5];
  const float* b1   = (const float*)d_in[6];
  const float* W2   = (const float*)d_in[7];
  const float* b2   = (const float*)d_in[8];
  const float* Wf1  = (const float*)d_in[9];
  const float* bf1  = (const float*)d_in[10];
  const float* g1   = (const float*)d_in[11];
  const float* be1  = (const float*)d_in[12];
  const float* Wf2  = (const float*)d_in[13];
  const float* bf2  = (const float*)d_in[14];
  const float* g2   = (const float*)d_in[15];
  const float* be2  = (const float*)d_in[16];
  const float* Wf3  = (const float*)d_in[17];
  const float* bf3  = (const float*)d_in[18];
  float* out = (float*)d_out;

  char* ws = (char*)d_ws;
  size_t off = 0;
  auto alloc = [&](size_t bytes) -> void* {
    void* p = ws + off;
    off = (off + bytes + 255) & ~(size_t)255;
    return p;
  };
  // zero-init region first (gcursor, gcnt, hg_sum)
  int*      gcursor = (int*)alloc(NBK * 4);
  int*      gcnt    = (int*)alloc(N_GRAPHS * 4);
  float*    hg_sum  = (float*)alloc(N_GRAPHS * D2 * 4);
  size_t zero_bytes = off;
  int*      deg     = (int*)alloc(N_NODES * 4);
  int*      row_off = (int*)alloc(N_NODES * 4);
  unsigned* packed  = (unsigned*)alloc((size_t)NBK * BKCAP * 4);
  int*      csr     = (int*)alloc((size_t)NBK * BKCAP * 4);
  __half*   p1h     = (__half*)alloc((size_t)N_NODES * D1 * 2);
  __half*   p2h     = (__half*)alloc((size_t)N_NODES * 32 * 2);   // padded rows (64B)
  float*    y1      = (float*)alloc((size_t)N_GRAPHS * DF1 * 4);
  float*    y2      = (float*)alloc((size_t)N_GRAPHS * DF2 * 4);
  float*    mu1     = (float*)alloc(DF1 * 4);
  float*    rstd1   = (float*)alloc(DF1 * 4);
  float*    mu2     = (float*)alloc(DF2 * 4);
  float*    rstd2   = (float*)alloc(DF2 * 4);

  hipMemsetAsync(d_ws, 0, zero_bytes, stream);

  k_scatter2<<<NBLK1, 256, 0, stream>>>(src, dst, gcursor, packed);
  k_bfine2<<<NBK, 256, 0, stream>>>(packed, gcursor, csr, deg, row_off);
  k_gemm1<<<N_NODES / 80, 256, 0, stream>>>(feat, W1, p1h);
  k_agg1<<<N_NODES / 4, 256, 0, stream>>>(p1h, deg, row_off, csr, b1, W2, p2h);
  k_agg2<<<(N_NODES * 10 + 255) / 256, 256, 0, stream>>>(p2h, deg, row_off, csr, b2, n2g, hg_sum, gcnt);
  k_mlp1<<<N_GRAPHS, 128, 0, stream>>>(hg_sum, gcnt, sf, Wf1, bf1, y1);
  k_bnstats<<<DF1, 256, 0, stream>>>(y1, DF1, mu1, rstd1);
  k_mlp2<<<(N_GRAPHS * DF2) / 256, 256, 0, stream>>>(y1, mu1, rstd1, g1, be1, Wf2, bf2, y2);
  k_bnstats<<<DF2, 256, 0, stream>>>(y2, DF2, mu2, rstd2);
  k_mlp3<<<(N_GRAPHS * DOUT) / 256, 256, 0, stream>>>(y2, mu2, rstd2, g2, be2, Wf3, bf3, out);
}